// Round 9
// baseline (115.083 us; speedup 1.0000x reference)
//
#include <hip/hip_runtime.h>

// InteractionLayer (SchNet-style) — MFMA f16, barrier-free main loop. gfx950.
// Shapes hardcoded: B=4, N=256, NF=H=128, K=300 filters, gamma=10, spacing=0.1.
// Block = one (b,i) row: 1024 blocks x 512 threads (8 waves).
// NEW STRUCTURE: each wave owns 16 sorted j-rows x ALL 128 h; 256 j's done in
// 2 outer iterations of 128 rows. ytile rows are wave-private -> GEMM1-write /
// GEMM2-read needs only in-wave lgkmcnt ordering: ZERO barriers in the main
// loop (round-8 counters: 43% stall with 8 barriers/loop at 2 blocks/CU).
// Also: rbf computed ONCE per row (was duplicated across hgrp-pair waves), and
// the rank-sort is split across all 512 threads (2x128 partial scans, summed).
// Registers: ONE merged f32x4 acc[8] for GEMM1/GEMM2 (32 AGPRs) + sumv[8]
// (~40 extra regs/wave vs round-6's fatal 72 -> no spill expected; watch
// FETCH/WRITE for the spill signature).
// GEMM1: rbf[rows x 320k] @ W1[320x128]; rbf exact exp-recurrence in regs;
//   K-steps restricted per wave's 16-row group (window +-12).
// GEMM2: ssp(y) @ W2[128x128] dense. W1/W2 B-frags straight from global
//   (pre-packed fragment layout, L1/L2-resident).
// ssp in log2 domain: ssp(x) = ln2*log2(0.5*exp2(x*log2e)+0.5); sum_j kept in
// log2 domain, ln2 applied once in the reduction.
//
// MFMA 16x16x32 layouts (gfx950):
//   A: lane l elem j -> A[l&15][(l>>4)*8 + j]
//   B: lane l elem j -> B[(l>>4)*8 + j][l&15]
//   D: lane l reg  r -> D[(l>>4)*4 + r][l&15]

typedef _Float16 f16x8 __attribute__((ext_vector_type(8)));
typedef float f32x4 __attribute__((ext_vector_type(4)));

__device__ __forceinline__ float exp2f_fast(float x) {
#if __has_builtin(__builtin_amdgcn_exp2f)
  return __builtin_amdgcn_exp2f(x);
#else
  return __exp2f(x);
#endif
}
__device__ __forceinline__ float log2f_fast(float x) {
#if __has_builtin(__builtin_amdgcn_logf)
  return __builtin_amdgcn_logf(x);
#else
  return __log2f(x);
#endif
}

// log2-domain ssp: log2(0.5*e^x + 0.5).  ssp(x) = ln2 * ssp_l2(x).
__device__ __forceinline__ float ssp_l2(float x) {
  return log2f_fast(fmaf(0.5f, exp2f_fast(1.44269504f * x), 0.5f));
}

// Pack W1 [300,128] -> f16 B-frag layout [10kk][8nt][64l][8j] at ws[0..40960)
// and W2 [128,128] -> [4kk][8nt][64l][8j] at ws[40960..57344).
__global__ void prep_pack(const float* __restrict__ W1, const float* __restrict__ W2,
                          unsigned short* __restrict__ ws) {
  int gid = blockIdx.x * 256 + threadIdx.x;
  if (gid < 40960) {
    int j = gid & 7, l = (gid >> 3) & 63, ntg = (gid >> 9) & 7, kk = gid >> 12;
    int k = kk * 32 + (l >> 4) * 8 + j;
    int h = ntg * 16 + (l & 15);
    float v = (k < 300) ? W1[k * 128 + h] : 0.f;
    ws[gid] = __builtin_bit_cast(unsigned short, (_Float16)v);
  } else if (gid < 57344) {
    int g2 = gid - 40960;
    int j = g2 & 7, l = (g2 >> 3) & 63, ntg = (g2 >> 9) & 7, kk = g2 >> 12;
    int k = kk * 32 + (l >> 4) * 8 + j;
    int h = ntg * 16 + (l & 15);
    ws[gid] = __builtin_bit_cast(unsigned short, (_Float16)W2[k * 128 + h]);
  }
}

__global__ __launch_bounds__(512, 4) void interaction_kernel(
    const float* __restrict__ nodef, const float* __restrict__ pos,
    const float* __restrict__ valid, const unsigned short* __restrict__ ws,
    const float* __restrict__ Wa1, const float* __restrict__ Wa2,
    const float* __restrict__ Wa3, float* __restrict__ out) {
  __shared__ __align__(16) _Float16 ytile[128 * 136];  // 34,816 B; rows wave-private
  __shared__ float d_lds[256];
  __shared__ int k0arr[256];
  __shared__ unsigned short jord[256];
  __shared__ unsigned short pr[2][256];
  __shared__ int kklo[16], kkhi[16];
  __shared__ float xrow[128], h1row[128], hhrow[128], a2row[128];
  __shared__ float partial[4][128];
  __shared__ float red[32][128];  // separate from ytile (waves finish at own pace)

  const int t = threadIdx.x;
  const int bid = blockIdx.x;  // b*256 + i
  const int b = bid >> 8;
  const unsigned short* __restrict__ W2g = ws + 40960;

  if (t < 128) xrow[t] = nodef[bid * 128 + t];
  if (t < 256) {
    const float qx = pos[bid * 3 + 0], qy = pos[bid * 3 + 1], qz = pos[bid * 3 + 2];
    const float px = pos[(b * 256 + t) * 3 + 0];
    const float py = pos[(b * 256 + t) * 3 + 1];
    const float pz = pos[(b * 256 + t) * 3 + 2];
    const float dx = px - qx, dy = py - qy, dz = pz - qz;
    const float dd = sqrtf(dx * dx + dy * dy + dz * dz);
    d_lds[t] = dd;
    k0arr[t] = __float2int_rn(dd * 10.f);
  }
  __syncthreads();

  // ---- rank-sort, parallelized: same comparisons as the proven serial sort,
  //      each thread scans 128 entries; partial ranks summed. Deterministic. ----
  {
    const int j = t & 255, half = t >> 8;
    const int key = k0arr[j];
    int rank = 0;
    const int base = half * 128;
    for (int j2 = base; j2 < base + 128; ++j2) {
      const int k2 = k0arr[j2];
      rank += (k2 < key || (k2 == key && j2 < j)) ? 1 : 0;
    }
    pr[half][j] = (unsigned short)rank;
  }
  // h1 = x @ Wa1 (partials over 4 thread-groups)
  {
    const int hh_ = t & 127, part = t >> 7;
    float a = 0.f;
#pragma unroll 8
    for (int k = part * 32; k < part * 32 + 32; ++k) a += xrow[k] * Wa1[k * 128 + hh_];
    partial[part][hh_] = a;
  }
  __syncthreads();
  if (t < 256) jord[pr[0][t] + pr[1][t]] = (unsigned short)t;
  if (t < 128)
    h1row[t] = partial[0][t] + partial[1][t] + partial[2][t] + partial[3][t];
  __syncthreads();
  // per sorted-16-group K-step ranges (window +-12: exp(-10*1.2^2)=5.6e-7)
  if (t < 16) {
    const int base = t * 16;
    const int klo = max(0, k0arr[jord[base]] - 12);
    const int khi = min(319, k0arr[jord[base + 15]] + 12);
    kklo[t] = klo >> 5;
    kkhi[t] = (khi >> 5) + 1;
  }
  __syncthreads();

  const int w = t >> 6, l = t & 63;
  const int lr = l & 15, lq = l >> 4;
  float sumv[8];
#pragma unroll
  for (int r = 0; r < 8; ++r) sumv[r] = 0.f;
  f32x4 acc[8];  // merged accumulator set for GEMM1 and GEMM2 (32 AGPRs)

  // ---- main loop: 2 outer iters x (wave-private 16 rows x 128 h). NO BARRIERS.
  for (int it = 0; it < 2; ++it) {
    const int g = it * 8 + w;  // sorted 16-row group owned by this wave
    const float dd = d_lds[jord[it * 128 + w * 16 + lr]];
    const int lo = kklo[g], hi = kkhi[g];

    // GEMM1: 16j x 128h, K-steps restricted to this wave's window.
#pragma unroll
    for (int r = 0; r < 8; ++r) acc[r] = f32x4{0, 0, 0, 0};
    for (int kk = lo; kk < hi; ++kk) {
      // rbf via exact exp recurrence: a_j = -10*(x0-0.1j)^2;
      // a_{j+1}-a_j = 2x0-0.2j-0.1 -> v *= r, r *= e^-0.2. Underflow -> exact 0.
      const float x0 = dd - 0.1f * (float)(kk * 32 + lq * 8);
      float v = exp2f_fast(-14.4269504f * x0 * x0);                // e^{a_0}
      float r = exp2f_fast(fmaf(2.88539008f, x0, -0.144269504f));  // e^{2x0-0.1}
      f16x8 afr;
      afr[0] = (_Float16)v;
#pragma unroll
      for (int j = 1; j < 8; ++j) {
        v *= r;
        r *= 0.818730753f;  // e^-0.2
        afr[j] = (_Float16)v;
      }
#pragma unroll
      for (int nt = 0; nt < 8; ++nt) {
        const f16x8 bfr = *(const f16x8*)&ws[((kk * 8 + nt) * 64 + l) * 8];
        acc[nt] = __builtin_amdgcn_mfma_f32_16x16x32_f16(afr, bfr, acc[nt], 0, 0, 0);
      }
    }
    // ssp -> wave-private ytile rows (in-wave LDS ordering; no barrier)
#pragma unroll
    for (int nt = 0; nt < 8; ++nt)
#pragma unroll
      for (int r = 0; r < 4; ++r)
        ytile[(w * 16 + lq * 4 + r) * 136 + nt * 16 + lr] =
            (_Float16)(0.69314718f * ssp_l2(acc[nt][r]));

    // GEMM2: z = y @ W2 (dense K=128), same acc registers.
#pragma unroll
    for (int r = 0; r < 8; ++r) acc[r] = f32x4{0, 0, 0, 0};
#pragma unroll
    for (int kk = 0; kk < 4; ++kk) {
      const f16x8 afr = *(const f16x8*)&ytile[(w * 16 + lr) * 136 + kk * 32 + lq * 8];
#pragma unroll
      for (int nt = 0; nt < 8; ++nt) {
        const f16x8 bfr = *(const f16x8*)&W2g[((kk * 8 + nt) * 64 + l) * 8];
        acc[nt] = __builtin_amdgcn_mfma_f32_16x16x32_f16(afr, bfr, acc[nt], 0, 0, 0);
      }
    }
    // accumulate sum_j in log2 domain (ln2 applied once in the reduction)
#pragma unroll
    for (int nt = 0; nt < 8; ++nt)
#pragma unroll
      for (int r = 0; r < 4; ++r) sumv[nt] += ssp_l2(acc[nt][r]);
  }

  // ---- reduce sum_j partials: 8 waves x 4 lq-groups = 32 per h-column ----
  __syncthreads();  // all waves done with main loop
#pragma unroll
  for (int nt = 0; nt < 8; ++nt)
    red[w * 4 + lq][nt * 16 + lr] = 0.69314718f * sumv[nt];
  __syncthreads();
  if (t < 128) {
    float s = 0.f;
#pragma unroll
    for (int q = 0; q < 32; ++q) s += red[q][t];
    hhrow[t] = h1row[t] * s;  // CFConv: h * sum_j filt
  }
  __syncthreads();
  // a2 = ssp(hh @ Wa2)
  {
    const int hh_ = t & 127, part = t >> 7;
    float a = 0.f;
#pragma unroll 8
    for (int k = part * 32; k < part * 32 + 32; ++k) a += hhrow[k] * Wa2[k * 128 + hh_];
    partial[part][hh_] = a;
  }
  __syncthreads();
  if (t < 128)
    a2row[t] = 0.69314718f *
               ssp_l2(partial[0][t] + partial[1][t] + partial[2][t] + partial[3][t]);
  __syncthreads();
  // out = x + (a2 @ Wa3) * valid
  {
    const int hh_ = t & 127, part = t >> 7;
    float a = 0.f;
#pragma unroll 8
    for (int k = part * 32; k < part * 32 + 32; ++k) a += a2row[k] * Wa3[k * 128 + hh_];
    partial[part][hh_] = a;
  }
  __syncthreads();
  if (t < 128)
    out[bid * 128 + t] =
        xrow[t] + (partial[0][t] + partial[1][t] + partial[2][t] + partial[3][t]) * valid[bid];
}

extern "C" void kernel_launch(void* const* d_in, const int* in_sizes, int n_in,
                              void* d_out, int out_size, void* d_ws, size_t ws_size,
                              hipStream_t stream) {
  const float* nodef = (const float*)d_in[0];
  const float* pos   = (const float*)d_in[1];
  const float* valid = (const float*)d_in[2];
  const float* W1    = (const float*)d_in[3];
  const float* W2    = (const float*)d_in[4];
  const float* Wa1   = (const float*)d_in[5];
  const float* Wa2   = (const float*)d_in[6];
  const float* Wa3   = (const float*)d_in[7];
  float* outp = (float*)d_out;
  unsigned short* wsp = (unsigned short*)d_ws;  // 57,344 f16 = 114,688 B

  prep_pack<<<224, 256, 0, stream>>>(W1, W2, wsp);
  interaction_kernel<<<1024, 512, 0, stream>>>(nodef, pos, valid, wsp,
                                               Wa1, Wa2, Wa3, outp);
}

// Round 10
// 57.199 us; speedup vs baseline: 2.0120x; 2.0120x over previous
//
#include <hip/hip_runtime.h>

// InteractionLayer (SchNet-style) — MFMA f16, round-8 base + dbuf/1-barrier. gfx950.
// Shapes hardcoded: B=4, N=256, NF=H=128, K=300 filters, gamma=10, spacing=0.1.
// Block = one (b,i) row: 1024 blocks x 512 threads (8 waves: jg 0..3 x hgrp 0..1).
// Wave tile 16j x 64h with ONE merged f32x4 acc[4] — the proven register budget
// [rounds 6/9: acc[8] variants spill catastrophically; acc[4] is the ceiling].
// Deltas vs round 8 (59.1 us):
//  1. parallel rank-sort (proven round 9): 512 threads x 128-entry scans.
//  2. ytile double-buffered -> ONE barrier per chunk (4 total, was 8).
//     Safety: only same-buffer conflict is W_{c+1} vs R_{c-1}; R_{c-1} < W_c < B_c
//     and W_{c+1} > B_c, so the barrier rendezvous orders them.
// GEMM1: rbf[64j x 320k] @ W1[320x128]; rbf exact exp-recurrence in regs;
//   K-steps restricted per sorted 16-row group (window +-12).
// GEMM2: ssp(y)[64x128] @ W2[128x128] dense.
// W1/W2 B-fragments read directly from global (pre-packed, L1/L2-resident).
// ssp in log2 domain: ssp(x) = ln2*log2(0.5*exp2(x*log2e)+0.5); sum_j kept in
// log2 domain, ln2 applied once in the reduction.
//
// MFMA 16x16x32 layouts (gfx950):
//   A: lane l elem j -> A[l&15][(l>>4)*8 + j]
//   B: lane l elem j -> B[(l>>4)*8 + j][l&15]
//   D: lane l reg  r -> D[(l>>4)*4 + r][l&15]

typedef _Float16 f16x8 __attribute__((ext_vector_type(8)));
typedef float f32x4 __attribute__((ext_vector_type(4)));

__device__ __forceinline__ float exp2f_fast(float x) {
#if __has_builtin(__builtin_amdgcn_exp2f)
  return __builtin_amdgcn_exp2f(x);
#else
  return __exp2f(x);
#endif
}
__device__ __forceinline__ float log2f_fast(float x) {
#if __has_builtin(__builtin_amdgcn_logf)
  return __builtin_amdgcn_logf(x);
#else
  return __log2f(x);
#endif
}

// log2-domain ssp: log2(0.5*e^x + 0.5).  ssp(x) = ln2 * ssp_l2(x).
__device__ __forceinline__ float ssp_l2(float x) {
  return log2f_fast(fmaf(0.5f, exp2f_fast(1.44269504f * x), 0.5f));
}

// Pack W1 [300,128] -> f16 B-frag layout [10kk][8nt][64l][8j] at ws[0..40960)
// and W2 [128,128] -> [4kk][8nt][64l][8j] at ws[40960..57344).
__global__ void prep_pack(const float* __restrict__ W1, const float* __restrict__ W2,
                          unsigned short* __restrict__ ws) {
  int gid = blockIdx.x * 256 + threadIdx.x;
  if (gid < 40960) {
    int j = gid & 7, l = (gid >> 3) & 63, ntg = (gid >> 9) & 7, kk = gid >> 12;
    int k = kk * 32 + (l >> 4) * 8 + j;
    int h = ntg * 16 + (l & 15);
    float v = (k < 300) ? W1[k * 128 + h] : 0.f;
    ws[gid] = __builtin_bit_cast(unsigned short, (_Float16)v);
  } else if (gid < 57344) {
    int g2 = gid - 40960;
    int j = g2 & 7, l = (g2 >> 3) & 63, ntg = (g2 >> 9) & 7, kk = g2 >> 12;
    int k = kk * 32 + (l >> 4) * 8 + j;
    int h = ntg * 16 + (l & 15);
    ws[gid] = __builtin_bit_cast(unsigned short, (_Float16)W2[k * 128 + h]);
  }
}

__global__ __launch_bounds__(512, 4) void interaction_kernel(
    const float* __restrict__ nodef, const float* __restrict__ pos,
    const float* __restrict__ valid, const unsigned short* __restrict__ ws,
    const float* __restrict__ Wa1, const float* __restrict__ Wa2,
    const float* __restrict__ Wa3, float* __restrict__ out) {
  __shared__ __align__(16) _Float16 ytile[2][64 * 136];  // 34,816 B double-buffered
  __shared__ float d_lds[256];
  __shared__ int k0arr[256];
  __shared__ unsigned short jord[256];
  __shared__ unsigned short pr[2][256];
  __shared__ int kklo[16], kkhi[16];
  __shared__ float xrow[128], h1row[128], hhrow[128], a2row[128];
  __shared__ float partial[4][128];

  const int t = threadIdx.x;
  const int bid = blockIdx.x;  // b*256 + i
  const int b = bid >> 8;
  const unsigned short* __restrict__ W2g = ws + 40960;

  if (t < 128) xrow[t] = nodef[bid * 128 + t];
  if (t < 256) {
    const float qx = pos[bid * 3 + 0], qy = pos[bid * 3 + 1], qz = pos[bid * 3 + 2];
    const float px = pos[(b * 256 + t) * 3 + 0];
    const float py = pos[(b * 256 + t) * 3 + 1];
    const float pz = pos[(b * 256 + t) * 3 + 2];
    const float dx = px - qx, dy = py - qy, dz = pz - qz;
    const float dd = sqrtf(dx * dx + dy * dy + dz * dz);
    d_lds[t] = dd;
    k0arr[t] = __float2int_rn(dd * 10.f);
  }
  __syncthreads();

  // ---- rank-sort, parallelized (proven round 9): 512 threads x 128 scans ----
  {
    const int j = t & 255, half = t >> 8;
    const int key = k0arr[j];
    int rank = 0;
    const int base = half * 128;
    for (int j2 = base; j2 < base + 128; ++j2) {
      const int k2 = k0arr[j2];
      rank += (k2 < key || (k2 == key && j2 < j)) ? 1 : 0;
    }
    pr[half][j] = (unsigned short)rank;
  }
  // h1 = x @ Wa1 (partials over 4 thread-groups)
  {
    const int hh_ = t & 127, part = t >> 7;
    float a = 0.f;
#pragma unroll 8
    for (int k = part * 32; k < part * 32 + 32; ++k) a += xrow[k] * Wa1[k * 128 + hh_];
    partial[part][hh_] = a;
  }
  __syncthreads();
  if (t < 256) jord[pr[0][t] + pr[1][t]] = (unsigned short)t;
  if (t < 128)
    h1row[t] = partial[0][t] + partial[1][t] + partial[2][t] + partial[3][t];
  __syncthreads();
  // per sorted-16-group K-step ranges (window +-12: exp(-10*1.2^2)=5.6e-7)
  if (t < 16) {
    const int base = t * 16;
    const int klo = max(0, k0arr[jord[base]] - 12);
    const int khi = min(319, k0arr[jord[base + 15]] + 12);
    kklo[t] = klo >> 5;
    kkhi[t] = (khi >> 5) + 1;
  }
  __syncthreads();

  const int wid = t >> 6, l = t & 63;
  const int jg = wid >> 1, hgrp = wid & 1;  // wave tile: 16 j-rows x 64 h-cols
  const int lr = l & 15, lq = l >> 4;
  float sumv[4] = {0.f, 0.f, 0.f, 0.f};
  f32x4 acc[4];  // ONE accumulator set, reused by GEMM1 and GEMM2 (reg-lean)

  // ---- main loop: 4 chunks of 64 sorted j's; ONE barrier per chunk ----
  for (int cc = 0; cc < 4; ++cc) {
    const int buf = cc & 1;
    const int g = cc * 4 + jg;
    const float dd = d_lds[jord[cc * 64 + jg * 16 + lr]];
    const int lo = kklo[g], hi = kkhi[g];

    // GEMM1: 16j x 64h, K-steps restricted to group window.
#pragma unroll
    for (int r = 0; r < 4; ++r) acc[r] = f32x4{0, 0, 0, 0};
    for (int kk = lo; kk < hi; ++kk) {
      // rbf via exact exp recurrence: a_j = -10*(x0-0.1j)^2;
      // a_{j+1}-a_j = 2x0-0.2j-0.1 -> v *= r, r *= e^-0.2. Underflow -> exact 0.
      const float x0 = dd - 0.1f * (float)(kk * 32 + lq * 8);
      float v = exp2f_fast(-14.4269504f * x0 * x0);                // e^{a_0}
      float r = exp2f_fast(fmaf(2.88539008f, x0, -0.144269504f));  // e^{2x0-0.1}
      f16x8 afr;
      afr[0] = (_Float16)v;
#pragma unroll
      for (int j = 1; j < 8; ++j) {
        v *= r;
        r *= 0.818730753f;  // e^-0.2
        afr[j] = (_Float16)v;
      }
#pragma unroll
      for (int nt = 0; nt < 4; ++nt) {
        const f16x8 bfr = *(const f16x8*)&ws[((kk * 8 + hgrp * 4 + nt) * 64 + l) * 8];
        acc[nt] = __builtin_amdgcn_mfma_f32_16x16x32_f16(afr, bfr, acc[nt], 0, 0, 0);
      }
    }
    // ssp -> y tile (f16), current buffer
#pragma unroll
    for (int nt = 0; nt < 4; ++nt)
#pragma unroll
      for (int r = 0; r < 4; ++r)
        ytile[buf][(jg * 16 + lq * 4 + r) * 136 + hgrp * 64 + nt * 16 + lr] =
            (_Float16)(0.69314718f * ssp_l2(acc[nt][r]));
    __syncthreads();  // the ONLY barrier: orders this chunk's W before its R

    // GEMM2: z = y @ W2 (dense K=128), same acc registers.
#pragma unroll
    for (int r = 0; r < 4; ++r) acc[r] = f32x4{0, 0, 0, 0};
#pragma unroll
    for (int kk = 0; kk < 4; ++kk) {
      const f16x8 afr =
          *(const f16x8*)&ytile[buf][(jg * 16 + lr) * 136 + kk * 32 + lq * 8];
#pragma unroll
      for (int nt = 0; nt < 4; ++nt) {
        const f16x8 bfr = *(const f16x8*)&W2g[((kk * 8 + hgrp * 4 + nt) * 64 + l) * 8];
        acc[nt] = __builtin_amdgcn_mfma_f32_16x16x32_f16(afr, bfr, acc[nt], 0, 0, 0);
      }
    }
    // accumulate sum_j in log2 domain (ln2 applied once in the reduction)
#pragma unroll
    for (int nt = 0; nt < 4; ++nt)
#pragma unroll
      for (int r = 0; r < 4; ++r) sumv[nt] += ssp_l2(acc[nt][r]);
    // no second barrier: next chunk writes the OTHER buffer (see header proof)
  }

  // ---- reduce sum_j partials (16 per h-column); f32 scratch over ytile[0].
  // Last readers of ytile[0] (chunk 2's GEMM2) finished before barrier B_3;
  // these writes happen after B_3 in program order -> safe without a barrier.
  {
    float* red = (float*)&ytile[0][0];
#pragma unroll
    for (int nt = 0; nt < 4; ++nt)
      red[(jg * 4 + lq) * 128 + hgrp * 64 + nt * 16 + lr] = 0.69314718f * sumv[nt];
  }
  __syncthreads();
  if (t < 128) {
    const float* red = (const float*)&ytile[0][0];
    float s = 0.f;
#pragma unroll
    for (int q = 0; q < 16; ++q) s += red[q * 128 + t];
    hhrow[t] = h1row[t] * s;  // CFConv: h * sum_j filt
  }
  __syncthreads();
  // a2 = ssp(hh @ Wa2)
  {
    const int hh_ = t & 127, part = t >> 7;
    float a = 0.f;
#pragma unroll 8
    for (int k = part * 32; k < part * 32 + 32; ++k) a += hhrow[k] * Wa2[k * 128 + hh_];
    partial[part][hh_] = a;
  }
  __syncthreads();
  if (t < 128)
    a2row[t] = 0.69314718f *
               ssp_l2(partial[0][t] + partial[1][t] + partial[2][t] + partial[3][t]);
  __syncthreads();
  // out = x + (a2 @ Wa3) * valid
  {
    const int hh_ = t & 127, part = t >> 7;
    float a = 0.f;
#pragma unroll 8
    for (int k = part * 32; k < part * 32 + 32; ++k) a += a2row[k] * Wa3[k * 128 + hh_];
    partial[part][hh_] = a;
  }
  __syncthreads();
  if (t < 128)
    out[bid * 128 + t] =
        xrow[t] + (partial[0][t] + partial[1][t] + partial[2][t] + partial[3][t]) * valid[bid];
}

extern "C" void kernel_launch(void* const* d_in, const int* in_sizes, int n_in,
                              void* d_out, int out_size, void* d_ws, size_t ws_size,
                              hipStream_t stream) {
  const float* nodef = (const float*)d_in[0];
  const float* pos   = (const float*)d_in[1];
  const float* valid = (const float*)d_in[2];
  const float* W1    = (const float*)d_in[3];
  const float* W2    = (const float*)d_in[4];
  const float* Wa1   = (const float*)d_in[5];
  const float* Wa2   = (const float*)d_in[6];
  const float* Wa3   = (const float*)d_in[7];
  float* outp = (float*)d_out;
  unsigned short* wsp = (unsigned short*)d_ws;  // 57,344 f16 = 114,688 B

  prep_pack<<<224, 256, 0, stream>>>(W1, W2, wsp);
  interaction_kernel<<<1024, 512, 0, stream>>>(nodef, pos, valid, wsp,
                                               Wa1, Wa2, Wa3, outp);
}

// Round 11
// 53.681 us; speedup vs baseline: 2.1438x; 1.0655x over previous
//
#include <hip/hip_runtime.h>

// InteractionLayer (SchNet-style) — MFMA f16. Round-10 base + W2-in-LDS (proven
// rounds 2/3, worth ~3us vs global) + GEMM1 B-frag register prefetch. gfx950.
// Shapes hardcoded: B=4, N=256, NF=H=128, K=300 filters, gamma=10, spacing=0.1.
// Block = one (b,i) row: 1024 blocks x 512 threads (8 waves: jg 0..3 x hgrp 0..1).
// Wave tile 16j x 64h, ONE merged f32x4 acc[4] [rounds 6/9: acc[8] spills; this
// is the ceiling]. Residency is register-pinned at 2 blocks/CU (rounds 3/5/8
// all ~36% occupancy regardless of LDS) — so this round SHORTENS the critical
// path instead of trying to hide it:
//  1. W2 B-frags staged to LDS once (ds_read ~12cyc vs ~200cyc L1/L2 global).
//  2. GEMM1 K-loop 1-deep software pipeline: prefetch kk+1's 4 B-frags into
//     regs during kk's rbf-recurrence + MFMAs (+~16-24 regs; 128-reg budget
//     check: 64 arch + 16 acc now, (512,4) caps allocator at 128 -> no spill).
// LDS ~75 KB -> 2 blocks/CU (150 <= 160 KB). Main loop: 1 barrier/chunk (dbuf).
// GEMM1: rbf[64j x 320k] @ W1[320x128]; rbf exact exp-recurrence in regs;
//   K-steps restricted per sorted 16-row group (window +-12).
// GEMM2: ssp(y)[64x128] @ W2[128x128] dense. W1 B-frags from global (pre-packed).
// ssp in log2 domain: ssp(x) = ln2*log2(0.5*exp2(x*log2e)+0.5).
//
// MFMA 16x16x32 layouts (gfx950):
//   A: lane l elem j -> A[l&15][(l>>4)*8 + j]
//   B: lane l elem j -> B[(l>>4)*8 + j][l&15]
//   D: lane l reg  r -> D[(l>>4)*4 + r][l&15]

typedef _Float16 f16x8 __attribute__((ext_vector_type(8)));
typedef float f32x4 __attribute__((ext_vector_type(4)));

__device__ __forceinline__ float exp2f_fast(float x) {
#if __has_builtin(__builtin_amdgcn_exp2f)
  return __builtin_amdgcn_exp2f(x);
#else
  return __exp2f(x);
#endif
}
__device__ __forceinline__ float log2f_fast(float x) {
#if __has_builtin(__builtin_amdgcn_logf)
  return __builtin_amdgcn_logf(x);
#else
  return __log2f(x);
#endif
}

// log2-domain ssp: log2(0.5*e^x + 0.5).  ssp(x) = ln2 * ssp_l2(x).
__device__ __forceinline__ float ssp_l2(float x) {
  return log2f_fast(fmaf(0.5f, exp2f_fast(1.44269504f * x), 0.5f));
}

// Pack W1 [300,128] -> f16 B-frag layout [10kk][8nt][64l][8j] at ws[0..40960)
// and W2 [128,128] -> [4kk][8nt][64l][8j] at ws[40960..57344).
__global__ void prep_pack(const float* __restrict__ W1, const float* __restrict__ W2,
                          unsigned short* __restrict__ ws) {
  int gid = blockIdx.x * 256 + threadIdx.x;
  if (gid < 40960) {
    int j = gid & 7, l = (gid >> 3) & 63, ntg = (gid >> 9) & 7, kk = gid >> 12;
    int k = kk * 32 + (l >> 4) * 8 + j;
    int h = ntg * 16 + (l & 15);
    float v = (k < 300) ? W1[k * 128 + h] : 0.f;
    ws[gid] = __builtin_bit_cast(unsigned short, (_Float16)v);
  } else if (gid < 57344) {
    int g2 = gid - 40960;
    int j = g2 & 7, l = (g2 >> 3) & 63, ntg = (g2 >> 9) & 7, kk = g2 >> 12;
    int k = kk * 32 + (l >> 4) * 8 + j;
    int h = ntg * 16 + (l & 15);
    ws[gid] = __builtin_bit_cast(unsigned short, (_Float16)W2[k * 128 + h]);
  }
}

__global__ __launch_bounds__(512, 4) void interaction_kernel(
    const float* __restrict__ nodef, const float* __restrict__ pos,
    const float* __restrict__ valid, const unsigned short* __restrict__ ws,
    const float* __restrict__ Wa1, const float* __restrict__ Wa2,
    const float* __restrict__ Wa3, float* __restrict__ out) {
  __shared__ __align__(16) _Float16 ytile[2][64 * 136];   // 34,816 B double-buffered
  __shared__ __align__(16) unsigned short W2pk[16384];    // 32,768 B
  __shared__ float d_lds[256];
  __shared__ int k0arr[256];
  __shared__ unsigned short jord[256];
  __shared__ unsigned short pr[2][256];
  __shared__ int kklo[16], kkhi[16];
  __shared__ float xrow[128], h1row[128], hhrow[128], a2row[128];
  __shared__ float partial[4][128];

  const int t = threadIdx.x;
  const int bid = blockIdx.x;  // b*256 + i
  const int b = bid >> 8;

  // ---- stage W2 fragments into LDS (16B coalesced; proven round 2/3) ----
  {
    const uint4* src = (const uint4*)(ws + 40960);
    uint4* d2 = (uint4*)W2pk;
    for (int i = t; i < 2048; i += 512) d2[i] = src[i];
  }
  if (t < 128) xrow[t] = nodef[bid * 128 + t];
  if (t < 256) {
    const float qx = pos[bid * 3 + 0], qy = pos[bid * 3 + 1], qz = pos[bid * 3 + 2];
    const float px = pos[(b * 256 + t) * 3 + 0];
    const float py = pos[(b * 256 + t) * 3 + 1];
    const float pz = pos[(b * 256 + t) * 3 + 2];
    const float dx = px - qx, dy = py - qy, dz = pz - qz;
    const float dd = sqrtf(dx * dx + dy * dy + dz * dz);
    d_lds[t] = dd;
    k0arr[t] = __float2int_rn(dd * 10.f);
  }
  __syncthreads();

  // ---- rank-sort, parallelized (proven round 9): 512 threads x 128 scans ----
  {
    const int j = t & 255, half = t >> 8;
    const int key = k0arr[j];
    int rank = 0;
    const int base = half * 128;
    for (int j2 = base; j2 < base + 128; ++j2) {
      const int k2 = k0arr[j2];
      rank += (k2 < key || (k2 == key && j2 < j)) ? 1 : 0;
    }
    pr[half][j] = (unsigned short)rank;
  }
  // h1 = x @ Wa1 (partials over 4 thread-groups)
  {
    const int hh_ = t & 127, part = t >> 7;
    float a = 0.f;
#pragma unroll 8
    for (int k = part * 32; k < part * 32 + 32; ++k) a += xrow[k] * Wa1[k * 128 + hh_];
    partial[part][hh_] = a;
  }
  __syncthreads();
  if (t < 256) jord[pr[0][t] + pr[1][t]] = (unsigned short)t;
  if (t < 128)
    h1row[t] = partial[0][t] + partial[1][t] + partial[2][t] + partial[3][t];
  __syncthreads();
  // per sorted-16-group K-step ranges (window +-12: exp(-10*1.2^2)=5.6e-7)
  if (t < 16) {
    const int base = t * 16;
    const int klo = max(0, k0arr[jord[base]] - 12);
    const int khi = min(319, k0arr[jord[base + 15]] + 12);
    kklo[t] = klo >> 5;
    kkhi[t] = (khi >> 5) + 1;
  }
  __syncthreads();

  const int wid = t >> 6, l = t & 63;
  const int jg = wid >> 1, hgrp = wid & 1;  // wave tile: 16 j-rows x 64 h-cols
  const int lr = l & 15, lq = l >> 4;
  float sumv[4] = {0.f, 0.f, 0.f, 0.f};
  f32x4 acc[4];  // ONE accumulator set, reused by GEMM1 and GEMM2 (reg-lean)

  // ---- main loop: 4 chunks of 64 sorted j's; ONE barrier per chunk ----
  for (int cc = 0; cc < 4; ++cc) {
    const int buf = cc & 1;
    const int g = cc * 4 + jg;
    const float dd = d_lds[jord[cc * 64 + jg * 16 + lr]];
    const int lo = kklo[g], hi = kkhi[g];  // wave-uniform (>=1 step)

    // GEMM1: 16j x 64h, K-steps restricted to group window.
    // 1-deep software pipeline: prefetch kk+1's B-frags during kk's rbf+MFMA.
#pragma unroll
    for (int r = 0; r < 4; ++r) acc[r] = f32x4{0, 0, 0, 0};
    f16x8 nb0, nb1, nb2, nb3;
    {
      const unsigned short* p = &ws[((lo * 8 + hgrp * 4) * 64 + l) * 8];
      nb0 = *(const f16x8*)(p + 0 * 512);
      nb1 = *(const f16x8*)(p + 1 * 512);
      nb2 = *(const f16x8*)(p + 2 * 512);
      nb3 = *(const f16x8*)(p + 3 * 512);
    }
    for (int kk = lo; kk < hi; ++kk) {
      const f16x8 cb0 = nb0, cb1 = nb1, cb2 = nb2, cb3 = nb3;
      if (kk + 1 < hi) {  // wave-uniform branch
        const unsigned short* p = &ws[(((kk + 1) * 8 + hgrp * 4) * 64 + l) * 8];
        nb0 = *(const f16x8*)(p + 0 * 512);
        nb1 = *(const f16x8*)(p + 1 * 512);
        nb2 = *(const f16x8*)(p + 2 * 512);
        nb3 = *(const f16x8*)(p + 3 * 512);
      }
      // rbf via exact exp recurrence: a_j = -10*(x0-0.1j)^2;
      // a_{j+1}-a_j = 2x0-0.2j-0.1 -> v *= r, r *= e^-0.2. Underflow -> exact 0.
      const float x0 = dd - 0.1f * (float)(kk * 32 + lq * 8);
      float v = exp2f_fast(-14.4269504f * x0 * x0);                // e^{a_0}
      float r = exp2f_fast(fmaf(2.88539008f, x0, -0.144269504f));  // e^{2x0-0.1}
      f16x8 afr;
      afr[0] = (_Float16)v;
#pragma unroll
      for (int j = 1; j < 8; ++j) {
        v *= r;
        r *= 0.818730753f;  // e^-0.2
        afr[j] = (_Float16)v;
      }
      acc[0] = __builtin_amdgcn_mfma_f32_16x16x32_f16(afr, cb0, acc[0], 0, 0, 0);
      acc[1] = __builtin_amdgcn_mfma_f32_16x16x32_f16(afr, cb1, acc[1], 0, 0, 0);
      acc[2] = __builtin_amdgcn_mfma_f32_16x16x32_f16(afr, cb2, acc[2], 0, 0, 0);
      acc[3] = __builtin_amdgcn_mfma_f32_16x16x32_f16(afr, cb3, acc[3], 0, 0, 0);
    }
    // ssp -> y tile (f16), current buffer
#pragma unroll
    for (int nt = 0; nt < 4; ++nt)
#pragma unroll
      for (int r = 0; r < 4; ++r)
        ytile[buf][(jg * 16 + lq * 4 + r) * 136 + hgrp * 64 + nt * 16 + lr] =
            (_Float16)(0.69314718f * ssp_l2(acc[nt][r]));
    __syncthreads();  // the ONLY barrier: orders this chunk's W before its R

    // GEMM2: z = y @ W2 (dense K=128) from LDS, same acc registers.
#pragma unroll
    for (int r = 0; r < 4; ++r) acc[r] = f32x4{0, 0, 0, 0};
#pragma unroll
    for (int kk = 0; kk < 4; ++kk) {
      const f16x8 afr =
          *(const f16x8*)&ytile[buf][(jg * 16 + lr) * 136 + kk * 32 + lq * 8];
#pragma unroll
      for (int nt = 0; nt < 4; ++nt) {
        const f16x8 bfr = *(const f16x8*)&W2pk[((kk * 8 + hgrp * 4 + nt) * 64 + l) * 8];
        acc[nt] = __builtin_amdgcn_mfma_f32_16x16x32_f16(afr, bfr, acc[nt], 0, 0, 0);
      }
    }
    // accumulate sum_j in log2 domain (ln2 applied once in the reduction)
#pragma unroll
    for (int nt = 0; nt < 4; ++nt)
#pragma unroll
      for (int r = 0; r < 4; ++r) sumv[nt] += ssp_l2(acc[nt][r]);
    // no second barrier: next chunk writes the OTHER buffer (round-10 proof)
  }

  // ---- reduce sum_j partials (16 per h-column); f32 scratch over ytile[0].
  {
    float* red = (float*)&ytile[0][0];
#pragma unroll
    for (int nt = 0; nt < 4; ++nt)
      red[(jg * 4 + lq) * 128 + hgrp * 64 + nt * 16 + lr] = 0.69314718f * sumv[nt];
  }
  __syncthreads();
  if (t < 128) {
    const float* red = (const float*)&ytile[0][0];
    float s = 0.f;
#pragma unroll
    for (int q = 0; q < 16; ++q) s += red[q * 128 + t];
    hhrow[t] = h1row[t] * s;  // CFConv: h * sum_j filt
  }
  __syncthreads();
  // a2 = ssp(hh @ Wa2)
  {
    const int hh_ = t & 127, part = t >> 7;
    float a = 0.f;
#pragma unroll 8
    for (int k = part * 32; k < part * 32 + 32; ++k) a += hhrow[k] * Wa2[k * 128 + hh_];
    partial[part][hh_] = a;
  }
  __syncthreads();
  if (t < 128)
    a2row[t] = 0.69314718f *
               ssp_l2(partial[0][t] + partial[1][t] + partial[2][t] + partial[3][t]);
  __syncthreads();
  // out = x + (a2 @ Wa3) * valid
  {
    const int hh_ = t & 127, part = t >> 7;
    float a = 0.f;
#pragma unroll 8
    for (int k = part * 32; k < part * 32 + 32; ++k) a += a2row[k] * Wa3[k * 128 + hh_];
    partial[part][hh_] = a;
  }
  __syncthreads();
  if (t < 128)
    out[bid * 128 + t] =
        xrow[t] + (partial[0][t] + partial[1][t] + partial[2][t] + partial[3][t]) * valid[bid];
}

extern "C" void kernel_launch(void* const* d_in, const int* in_sizes, int n_in,
                              void* d_out, int out_size, void* d_ws, size_t ws_size,
                              hipStream_t stream) {
  const float* nodef = (const float*)d_in[0];
  const float* pos   = (const float*)d_in[1];
  const float* valid = (const float*)d_in[2];
  const float* W1    = (const float*)d_in[3];
  const float* W2    = (const float*)d_in[4];
  const float* Wa1   = (const float*)d_in[5];
  const float* Wa2   = (const float*)d_in[6];
  const float* Wa3   = (const float*)d_in[7];
  float* outp = (float*)d_out;
  unsigned short* wsp = (unsigned short*)d_ws;  // 57,344 f16 = 114,688 B

  prep_pack<<<224, 256, 0, stream>>>(W1, W2, wsp);
  interaction_kernel<<<1024, 512, 0, stream>>>(nodef, pos, valid, wsp,
                                               Wa1, Wa2, Wa3, outp);
}